// Round 4
// baseline (220.320 us; speedup 1.0000x reference)
//
#include <hip/hip_runtime.h>
#include <math.h>

#define NATOMS 2048
#define DIM 64

typedef float f32x4 __attribute__((ext_vector_type(4)));  // native vec for nt-store

// 8 lanes per pair (g = lane>>3 -> pair p0+g, 8 pairs per wave-iter).
// q = lane&7 owns basis dims d0 = q*8 .. q*8+7 (consecutive -> sin recurrence)
// and output dims {4q..4q+3} U {32+4q..32+4q+3}.
//
// t[m] = sum_d sin((d+1)*pi*x/5)/x * w1[d][m]  (1/x folded into the
// recurrence seeds), reduced over the 8 lanes of the group: xor1/xor2 via
// v_add_f32_dpp quad_perm (VALU pipe), xor4 via ds_swizzle (only DS op).
// out[o] = sqrt(2/5) * sum_m t[m] * w2[m][o], sqrt(2/5) pre-folded into w2.

template <int CTRL>
__device__ __forceinline__ float dpp_add(float v) {
    // v + quad_perm<CTRL>(v); GCNDPPCombine fuses mov_dpp+add -> v_add_f32_dpp
    int m = __builtin_amdgcn_update_dpp(0, __float_as_int(v), CTRL, 0xF, 0xF, true);
    return v + __int_as_float(m);
}
__device__ __forceinline__ float swz_add_xor4(float v) {
    // BitMode: (xor_mask<<10)|(or<<5)|and -> xor 4 within 32 lanes
    return v + __int_as_float(__builtin_amdgcn_ds_swizzle(__float_as_int(v), 0x101F));
}

__global__ __launch_bounds__(256) void bessel_rbf_kernel(
    const float* __restrict__ atoms,
    const float* __restrict__ w1,   // (64,4)
    const float* __restrict__ w2,   // (4,64)
    float* __restrict__ out)        // (N,N,64)
{
    const int lane = threadIdx.x & 63;
    const int waveInBlock = threadIdx.x >> 6;
    const int q = lane & 7;
    const int g = lane >> 3;
    const int d0 = q * 8;

    // w1 rows d0..d0+7
    float w1r[8][4];
#pragma unroll
    for (int k = 0; k < 8; ++k) {
        float4 v = *reinterpret_cast<const float4*>(w1 + (d0 + k) * 4);
        w1r[k][0] = v.x; w1r[k][1] = v.y; w1r[k][2] = v.z; w1r[k][3] = v.w;
    }

    // w2 columns 4q..4q+3 (A) and 32+4q..32+4q+3 (B), pre-scaled by sqrt(2/5)
    const float PREF = 0.6324555320336759f; // sqrt(2/5)
    float w2a[4][4], w2b[4][4];
#pragma unroll
    for (int m = 0; m < 4; ++m) {
        float4 va = *reinterpret_cast<const float4*>(w2 + m * DIM + 4 * q);
        float4 vb = *reinterpret_cast<const float4*>(w2 + m * DIM + 32 + 4 * q);
        w2a[m][0] = va.x * PREF; w2a[m][1] = va.y * PREF;
        w2a[m][2] = va.z * PREF; w2a[m][3] = va.w * PREF;
        w2b[m][0] = vb.x * PREF; w2b[m][1] = vb.y * PREF;
        w2b[m][2] = vb.z * PREF; w2b[m][3] = vb.w * PREF;
    }

    const unsigned totalPairs = (unsigned)NATOMS * (unsigned)NATOMS;
    const unsigned wavesTotal = (unsigned)gridDim.x * (blockDim.x >> 6);
    const unsigned wid = (unsigned)blockIdx.x * (blockDim.x >> 6) + waveInBlock;

    const float dk1 = (float)(d0 + 1);  // per-lane constant

    f32x4* __restrict__ out4 = reinterpret_cast<f32x4*>(out);

#pragma unroll 1
    for (unsigned p0 = wid * 8; p0 < totalPairs; p0 += wavesTotal * 8) {
        // 8 divides the row length, so all 8 pairs share row i (wave-uniform).
        const int i = __builtin_amdgcn_readfirstlane((int)(p0 >> 11));
        const int j = (int)(p0 & (NATOMS - 1)) + g;

        const float ax = atoms[i * 3 + 0];
        const float ay = atoms[i * 3 + 1];
        const float az = atoms[i * 3 + 2];
        const float bx = atoms[j * 3 + 0];
        const float by = atoms[j * 3 + 1];
        const float bz = atoms[j * 3 + 2];

        const float dx = ax - bx, dy = ay - by, dz = az - bz;
        float x = __builtin_amdgcn_sqrtf(fmaf(dx, dx, fmaf(dy, dy, dz * dz)));
        x += 1e-8f;                              // x_ext (sin arg AND divisor)
        const float inv = __builtin_amdgcn_rcpf(x);
        const float xr  = x * 0.1f;              // step angle in revolutions

        // sin((d0+k+1)*2*pi*xr)/x via Chebyshev: s_{k+1} = 2c*s_k - s_{k-1}
        // (1/x folded into the seeds; the recurrence is linear so all s_k scale)
        float r0 = dk1 * xr;
        float r1 = r0 + xr;
        r0 = r0 - floorf(r0);
        r1 = r1 - floorf(r1);
        float rc = xr - floorf(xr);
        const float a0   = __builtin_amdgcn_sinf(r0) * inv;
        const float a1   = __builtin_amdgcn_sinf(r1) * inv;
        const float c1   = __builtin_amdgcn_cosf(rc);
        const float twoC = c1 + c1;

        float t[4];
#pragma unroll
        for (int m = 0; m < 4; ++m)
            t[m] = fmaf(a1, w1r[1][m], a0 * w1r[0][m]);
        float sp = a0, sc = a1;
#pragma unroll
        for (int k = 2; k < 8; ++k) {
            const float sn = fmaf(twoC, sc, -sp);
#pragma unroll
            for (int m = 0; m < 4; ++m)
                t[m] = fmaf(sn, w1r[k][m], t[m]);
            sp = sc; sc = sn;
        }

        // Reduce across the 8 lanes of this group.
        // xor1 = quad_perm [1,0,3,2] = 0xB1; xor2 = quad_perm [2,3,0,1] = 0x4E
#pragma unroll
        for (int m = 0; m < 4; ++m) {
            t[m] = dpp_add<0xB1>(t[m]);
            t[m] = dpp_add<0x4E>(t[m]);
            t[m] = swz_add_xor4(t[m]);
        }

        // Project to this lane's 8 outputs.
        f32x4 oA, oB;
        oA.x = fmaf(t[0], w2a[0][0], fmaf(t[1], w2a[1][0], fmaf(t[2], w2a[2][0], t[3] * w2a[3][0])));
        oA.y = fmaf(t[0], w2a[0][1], fmaf(t[1], w2a[1][1], fmaf(t[2], w2a[2][1], t[3] * w2a[3][1])));
        oA.z = fmaf(t[0], w2a[0][2], fmaf(t[1], w2a[1][2], fmaf(t[2], w2a[2][2], t[3] * w2a[3][2])));
        oA.w = fmaf(t[0], w2a[0][3], fmaf(t[1], w2a[1][3], fmaf(t[2], w2a[2][3], t[3] * w2a[3][3])));
        oB.x = fmaf(t[0], w2b[0][0], fmaf(t[1], w2b[1][0], fmaf(t[2], w2b[2][0], t[3] * w2b[3][0])));
        oB.y = fmaf(t[0], w2b[0][1], fmaf(t[1], w2b[1][1], fmaf(t[2], w2b[2][1], t[3] * w2b[3][1])));
        oB.z = fmaf(t[0], w2b[0][2], fmaf(t[1], w2b[1][2], fmaf(t[2], w2b[2][2], t[3] * w2b[3][2])));
        oB.w = fmaf(t[0], w2b[0][3], fmaf(t[1], w2b[1][3], fmaf(t[2], w2b[2][3], t[3] * w2b[3][3])));

        // Pair region = 256B = 16 float4s; store [0,128) and [128,256) halves.
        // Write-once 1 GB stream -> nontemporal.
        const size_t base = (size_t)(p0 + (unsigned)g) * 16;
        __builtin_nontemporal_store(oA, &out4[base + q]);
        __builtin_nontemporal_store(oB, &out4[base + 8 + q]);
    }
}

extern "C" void kernel_launch(void* const* d_in, const int* in_sizes, int n_in,
                              void* d_out, int out_size, void* d_ws, size_t ws_size,
                              hipStream_t stream) {
    const float* atoms = (const float*)d_in[0];
    const float* w1    = (const float*)d_in[1];
    const float* w2    = (const float*)d_in[2];
    float* out         = (float*)d_out;

    // 2048 blocks x 256 threads = 8192 waves; 8 pairs/wave/iter -> 64 iters.
    dim3 grid(2048), block(256);
    hipLaunchKernelGGL(bessel_rbf_kernel, grid, block, 0, stream, atoms, w1, w2, out);
}

// Round 5
// 200.276 us; speedup vs baseline: 1.1001x; 1.1001x over previous
//
#include <hip/hip_runtime.h>
#include <math.h>

#define NATOMS 2048
#define DIM 64

typedef float f32x4 __attribute__((ext_vector_type(4)));

// Layout: 8 lanes per pair (group g = lane>>3), 8 pairs per wave-iteration.
// q = lane&7 owns basis dims d0 = q*8..q*8+7 (consecutive -> sin Chebyshev
// recurrence) and output dims {4q..4q+3} U {32+4q..32+4q+3}.
//
// Each wave owns a CONTIGUOUS 512-pair chunk (quarter output row):
//   i = wid>>2 (loop-invariant!), columns (wid&3)*512 + iter*8 + g.
// All atoms staged in LDS once -> the steady-state loop has NO global loads,
// so no vmcnt waits ever drain the output stores (vmcnt is one in-order
// counter shared by loads and stores — global loads in the loop would
// implicitly serialize on prior stores).
//
// t[m] = sum_d sin((d+1)*pi*x/5)/x * w1[d][m] (1/x folded into recurrence
// seeds), reduced over 8 lanes: xor1/xor2 as v_add_f32_dpp quad_perm (VALU),
// xor4 as one ds_swizzle. out[o] = sqrt(2/5)*sum_m t[m]*w2[m][o] with
// sqrt(2/5) pre-folded into the w2 fragments.

template <int CTRL>
__device__ __forceinline__ float dpp_add(float v) {
    int m = __builtin_amdgcn_update_dpp(0, __float_as_int(v), CTRL, 0xF, 0xF, true);
    return v + __int_as_float(m);
}
__device__ __forceinline__ float swz_add_xor4(float v) {
    return v + __int_as_float(__builtin_amdgcn_ds_swizzle(__float_as_int(v), 0x101F));
}

__global__ __launch_bounds__(256) void bessel_rbf_kernel(
    const float* __restrict__ atoms,
    const float* __restrict__ w1,   // (64,4)
    const float* __restrict__ w2,   // (4,64)
    float* __restrict__ out)        // (N,N,64)
{
    __shared__ float s_at[NATOMS * 3];   // 24 KB, xyz interleaved

    const int tid  = threadIdx.x;
    const int lane = tid & 63;
    const int waveInBlock = tid >> 6;
    const int q = lane & 7;
    const int g = lane >> 3;
    const int d0 = q * 8;

    // Stage all atoms to LDS: 6144 floats = 1536 float4, 256 threads x 6.
    {
        const float4* ga = reinterpret_cast<const float4*>(atoms);
        float4* sa = reinterpret_cast<float4*>(s_at);
#pragma unroll
        for (int r = 0; r < 6; ++r)
            sa[tid + 256 * r] = ga[tid + 256 * r];
    }

    // w1 rows d0..d0+7
    float w1r[8][4];
#pragma unroll
    for (int k = 0; k < 8; ++k) {
        float4 v = *reinterpret_cast<const float4*>(w1 + (d0 + k) * 4);
        w1r[k][0] = v.x; w1r[k][1] = v.y; w1r[k][2] = v.z; w1r[k][3] = v.w;
    }
    // w2 columns 4q..4q+3 (A) and 32+4q..32+4q+3 (B), pre-scaled by sqrt(2/5)
    const float PREF = 0.6324555320336759f;
    float w2a[4][4], w2b[4][4];
#pragma unroll
    for (int m = 0; m < 4; ++m) {
        float4 va = *reinterpret_cast<const float4*>(w2 + m * DIM + 4 * q);
        float4 vb = *reinterpret_cast<const float4*>(w2 + m * DIM + 32 + 4 * q);
        w2a[m][0] = va.x * PREF; w2a[m][1] = va.y * PREF;
        w2a[m][2] = va.z * PREF; w2a[m][3] = va.w * PREF;
        w2b[m][0] = vb.x * PREF; w2b[m][1] = vb.y * PREF;
        w2b[m][2] = vb.z * PREF; w2b[m][3] = vb.w * PREF;
    }

    __syncthreads();

    // Wave-contiguous chunking: wave wid owns pairs [wid*512, wid*512+512).
    const unsigned wid = __builtin_amdgcn_readfirstlane(
        (unsigned)blockIdx.x * 4u + (unsigned)waveInBlock);
    const int i       = (int)(wid >> 2);          // loop-invariant row
    const int colBase = (int)(wid & 3u) * 512;

    // i-atom (wave-uniform, from LDS broadcast)
    const float ax = s_at[i * 3 + 0];
    const float ay = s_at[i * 3 + 1];
    const float az = s_at[i * 3 + 2];

    const float dk1 = (float)(d0 + 1);
    f32x4* __restrict__ out4 = reinterpret_cast<f32x4*>(out);
    const size_t rowBase = (size_t)i * 2048 + (size_t)colBase;

#pragma unroll 1
    for (int it = 0; it < 64; ++it) {
        const int j = colBase + it * 8 + g;

        const float bx = s_at[j * 3 + 0];
        const float by = s_at[j * 3 + 1];
        const float bz = s_at[j * 3 + 2];

        const float dx = ax - bx, dy = ay - by, dz = az - bz;
        float x = __builtin_amdgcn_sqrtf(fmaf(dx, dx, fmaf(dy, dy, dz * dz)));
        x += 1e-8f;                              // x_ext (sin arg AND divisor)
        const float inv = __builtin_amdgcn_rcpf(x);
        const float xr  = x * 0.1f;              // step angle in revolutions

        // sin((d0+k+1)*2*pi*xr)/x via Chebyshev: s_{k+1} = 2c*s_k - s_{k-1}
        float r0 = dk1 * xr;
        float r1 = r0 + xr;
        r0 = r0 - floorf(r0);
        r1 = r1 - floorf(r1);
        float rc = xr - floorf(xr);
        const float a0   = __builtin_amdgcn_sinf(r0) * inv;
        const float a1   = __builtin_amdgcn_sinf(r1) * inv;
        const float c1   = __builtin_amdgcn_cosf(rc);
        const float twoC = c1 + c1;

        float t[4];
#pragma unroll
        for (int m = 0; m < 4; ++m)
            t[m] = fmaf(a1, w1r[1][m], a0 * w1r[0][m]);
        float sp = a0, sc = a1;
#pragma unroll
        for (int k = 2; k < 8; ++k) {
            const float sn = fmaf(twoC, sc, -sp);
#pragma unroll
            for (int m = 0; m < 4; ++m)
                t[m] = fmaf(sn, w1r[k][m], t[m]);
            sp = sc; sc = sn;
        }

        // Reduce across the 8 lanes of this group.
#pragma unroll
        for (int m = 0; m < 4; ++m) {
            t[m] = dpp_add<0xB1>(t[m]);   // xor1: quad_perm [1,0,3,2]
            t[m] = dpp_add<0x4E>(t[m]);   // xor2: quad_perm [2,3,0,1]
            t[m] = swz_add_xor4(t[m]);    // xor4: ds_swizzle
        }

        // Project to this lane's 8 outputs.
        f32x4 oA, oB;
        oA.x = fmaf(t[0], w2a[0][0], fmaf(t[1], w2a[1][0], fmaf(t[2], w2a[2][0], t[3] * w2a[3][0])));
        oA.y = fmaf(t[0], w2a[0][1], fmaf(t[1], w2a[1][1], fmaf(t[2], w2a[2][1], t[3] * w2a[3][1])));
        oA.z = fmaf(t[0], w2a[0][2], fmaf(t[1], w2a[1][2], fmaf(t[2], w2a[2][2], t[3] * w2a[3][2])));
        oA.w = fmaf(t[0], w2a[0][3], fmaf(t[1], w2a[1][3], fmaf(t[2], w2a[2][3], t[3] * w2a[3][3])));
        oB.x = fmaf(t[0], w2b[0][0], fmaf(t[1], w2b[1][0], fmaf(t[2], w2b[2][0], t[3] * w2b[3][0])));
        oB.y = fmaf(t[0], w2b[0][1], fmaf(t[1], w2b[1][1], fmaf(t[2], w2b[2][1], t[3] * w2b[3][1])));
        oB.z = fmaf(t[0], w2b[0][2], fmaf(t[1], w2b[1][2], fmaf(t[2], w2b[2][2], t[3] * w2b[3][2])));
        oB.w = fmaf(t[0], w2b[0][3], fmaf(t[1], w2b[1][3], fmaf(t[2], w2b[2][3], t[3] * w2b[3][3])));

        const size_t base = (rowBase + (size_t)(it * 8 + g)) * 16;
        out4[base + q]     = oA;
        out4[base + 8 + q] = oB;
    }
}

extern "C" void kernel_launch(void* const* d_in, const int* in_sizes, int n_in,
                              void* d_out, int out_size, void* d_ws, size_t ws_size,
                              hipStream_t stream) {
    const float* atoms = (const float*)d_in[0];
    const float* w1    = (const float*)d_in[1];
    const float* w2    = (const float*)d_in[2];
    float* out         = (float*)d_out;

    // 2048 blocks x 256 threads = 8192 waves; each wave owns 512 contiguous
    // pairs (64 iterations x 8 pairs).
    dim3 grid(2048), block(256);
    hipLaunchKernelGGL(bessel_rbf_kernel, grid, block, 0, stream, atoms, w1, w2, out);
}